// Round 3
// baseline (200.517 us; speedup 1.0000x reference)
//
#include <hip/hip_runtime.h>
#include <math.h>

#define LL 8192
#define CC 256
#define SS 16

#define LOG2E 1.4426950408889634f
#define LN2   0.6931471805599453f

__device__ __forceinline__ float fexp2(float v){ return __builtin_amdgcn_exp2f(v); }
__device__ __forceinline__ float flog2v(float v){ return __builtin_amdgcn_logf(v); }

// softplus(z) = max(z,0) + ln2 * log2(1 + 2^(-|z|*log2e))
__device__ __forceinline__ float softplus(float z){
    float t = fexp2(-fabsf(z) * LOG2E);
    return fmaxf(z, 0.f) + LN2 * flog2v(1.f + t);
}

// ============ k_proj: fused GEMM producing dt (softplus), boa, cm ============
// Output cols: [0,256)=dt, colTile4: [0,16)=boa, [16,32)=cm, rest discard.
#define BM 64
#define BN 64
#define BK 32
#define XSTR 68

__global__ __launch_bounds__(256) void k_proj(
    const float* __restrict__ x,
    const float* __restrict__ Wdt, const float* __restrict__ bdt,
    const float* __restrict__ WB,  const float* __restrict__ bB,
    const float* __restrict__ WC,  const float* __restrict__ bC,
    const float* __restrict__ logA,
    float* __restrict__ dt, float* __restrict__ boa, float* __restrict__ cm)
{
    __shared__ float xs[BK*XSTR];   // [k][m] transposed x tile
    __shared__ float wsd[BK*BN];    // [k][n]

    const int tid     = threadIdx.x;
    const int colTile = blockIdx.x;      // 0..4
    const int row0    = blockIdx.y * BM; // 0..127 tiles
    const int n0      = colTile * BN;

    const int sr  = tid >> 3;            // 0..31
    const int sk4 = (tid & 7) * 4;       // 0..28
    const int wk  = tid >> 4;            // 0..15
    const int wn4 = (tid & 15) * 4;      // 0..60
    const int tn  = tid & 15, tm = tid >> 4;

    float4 xr[2], wr[2];

    // fetch tile k0 into registers
    #define FETCH(k0) do {                                                     \
        _Pragma("unroll")                                                      \
        for (int h2=0; h2<2; h2++)                                             \
            xr[h2] = *(const float4*)&x[(size_t)(row0 + sr + h2*32)*CC + (k0) + sk4]; \
        _Pragma("unroll")                                                      \
        for (int h2=0; h2<2; h2++){                                            \
            int k = (k0) + wk + h2*16;                                         \
            if (colTile < 4)      wr[h2] = *(const float4*)&Wdt[(size_t)k*CC + n0 + wn4]; \
            else if (wn4 < 16)    wr[h2] = *(const float4*)&WB[(size_t)k*SS + wn4];       \
            else if (wn4 < 32)    wr[h2] = *(const float4*)&WC[(size_t)k*SS + (wn4-16)];  \
            else                  wr[h2] = make_float4(0.f,0.f,0.f,0.f);       \
        }                                                                      \
    } while(0)

    FETCH(0);

    float acc[4][4];
    #pragma unroll
    for (int r=0;r<4;r++)
        #pragma unroll
        for (int j=0;j<4;j++) acc[r][j] = 0.f;

    for (int k0 = 0; k0 < CC; k0 += BK) {
        __syncthreads();   // previous tile's readers done
        #pragma unroll
        for (int h2=0; h2<2; h2++){
            int r = sr + h2*32;
            xs[(sk4+0)*XSTR + r] = xr[h2].x;
            xs[(sk4+1)*XSTR + r] = xr[h2].y;
            xs[(sk4+2)*XSTR + r] = xr[h2].z;
            xs[(sk4+3)*XSTR + r] = xr[h2].w;
            *(float4*)&wsd[(wk + h2*16)*BN + wn4] = wr[h2];
        }
        __syncthreads();
        if (k0 + BK < CC) FETCH(k0 + BK);   // global loads fly during compute

        #pragma unroll
        for (int kk = 0; kk < BK; kk++) {
            float4 av = *(const float4*)&xs[kk*XSTR + tm*4];
            float4 bv = *(const float4*)&wsd[kk*BN  + tn*4];
            const float* ap = &av.x; const float* bp = &bv.x;
            #pragma unroll
            for (int r=0;r<4;r++)
                #pragma unroll
                for (int j=0;j<4;j++)
                    acc[r][j] = fmaf(ap[r], bp[j], acc[r][j]);
        }
    }

    const int m0 = row0 + tm*4;
    if (colTile < 4) {
        const int cg = n0 + tn*4;
        float4 bb = *(const float4*)&bdt[cg];
        const float* bbp = &bb.x;
        #pragma unroll
        for (int r=0;r<4;r++){
            float o[4];
            #pragma unroll
            for (int j=0;j<4;j++)
                o[j] = softplus(0.01f + acc[r][j] + bbp[j]);
            *(float4*)&dt[(size_t)(m0+r)*CC + cg] = make_float4(o[0],o[1],o[2],o[3]);
        }
    } else if (tn < 4) {
        const int s4 = tn*4;
        float sc[4], bv[4];
        #pragma unroll
        for (int j=0;j<4;j++){
            float A = -fexp2(logA[s4+j] * LOG2E);
            sc[j] = LOG2E / A;
            bv[j] = bB[s4+j];
        }
        #pragma unroll
        for (int r=0;r<4;r++){
            float o[4];
            #pragma unroll
            for (int j=0;j<4;j++)
                o[j] = (1.f + acc[r][j] + bv[j]) * sc[j];
            *(float4*)&boa[(size_t)(m0+r)*SS + s4] = make_float4(o[0],o[1],o[2],o[3]);
        }
    } else if (tn < 8) {
        const int s4 = tn*4 - 16;
        float bv[4];
        #pragma unroll
        for (int j=0;j<4;j++) bv[j] = bC[s4+j];
        #pragma unroll
        for (int r=0;r<4;r++){
            float o[4];
            #pragma unroll
            for (int j=0;j<4;j++)
                o[j] = acc[r][j] + bv[j];
            *(float4*)&cm[(size_t)(m0+r)*SS + s4] = make_float4(o[0],o[1],o[2],o[3]);
        }
    }
    #undef FETCH
}

// ============ k_scan1: thread=(c,s); per-chunk aggregates ====================
// block: 256 thr = 16 channels x 16 states; grid (16, GG)
__global__ __launch_bounds__(256) void k_scan1(const float* __restrict__ dt,
    const float* __restrict__ x, const float* __restrict__ boa,
    const float* __restrict__ logA,
    float* __restrict__ Ap, float* __restrict__ Hl, int TT)
{
    const int tid = threadIdx.x;
    const int s   = tid & 15;
    const int cl  = tid >> 4;
    const int c   = blockIdx.x * 16 + cl;
    const int g   = blockIdx.y;

    const float als = -fexp2(logA[s]*LOG2E) * LOG2E;   // A * log2e

    const int row0 = g * TT;
    const float* __restrict__ dp = dt  + (size_t)row0*CC + c;
    const float* __restrict__ xp = x   + (size_t)row0*CC + c;
    const float* __restrict__ bp = boa + (size_t)row0*SS + s;

    // depth-2 prefetch pipeline (row0+1 always < LL since TT >= 2)
    float d0 = dp[0],  x0 = xp[0],  b0 = bp[0];
    float d1 = dp[CC], x1 = xp[CC], b1 = bp[SS];

    float Apr = 1.f, h = 0.f;
    for (int t = 0; t < TT; ++t) {
        float d2 = 0.f, x2 = 0.f, b2 = 0.f;
        if (t + 2 < TT) { d2 = dp[2*CC]; x2 = xp[2*CC]; b2 = bp[2*SS]; }
        float a = fexp2(d0 * als);
        float u = fexp2(fmaf(a, b0, -b0)) * x0;
        h = fmaf(a, h, u);
        Apr *= a;
        d0 = d1; x0 = x1; b0 = b1;
        d1 = d2; x1 = x2; b1 = b2;
        dp += CC; xp += CC; bp += SS;
    }

    const int j = blockIdx.x*256 + tid;   // = c*16 + s
    Ap[(size_t)g*(CC*SS) + j] = Apr;
    Hl[(size_t)g*(CC*SS) + j] = h;
}

// ============ k_carry: wave-per-chain Kogge-Stone over chunks ================
template<int PER>
__global__ __launch_bounds__(256) void k_carry(const float* __restrict__ Ap,
    const float* __restrict__ Hl, float* __restrict__ Cr)
{
    const int lane = threadIdx.x & 63;
    const int wv   = threadIdx.x >> 6;
    const int j    = blockIdx.x*4 + wv;       // chain id 0..4095
    const int NJ   = CC*SS;

    float a[PER], u[PER];
    const size_t base = (size_t)lane*PER*NJ + j;
    #pragma unroll
    for (int k=0;k<PER;k++){
        a[k] = Ap[base + (size_t)k*NJ];
        u[k] = Hl[base + (size_t)k*NJ];
    }
    // lane-local aggregate
    float Aag = 1.f, Uag = 0.f;
    #pragma unroll
    for (int k=0;k<PER;k++){ Uag = fmaf(a[k], Uag, u[k]); Aag *= a[k]; }
    // inclusive wave scan, compose (prev then cur): U = A_cur*U_prev + U_cur
    #pragma unroll
    for (int d=1; d<64; d<<=1){
        float Apv = __shfl_up(Aag, d);
        float Upv = __shfl_up(Uag, d);
        if (lane >= d){ Uag = fmaf(Aag, Upv, Uag); Aag *= Apv; }
    }
    // exclusive carry-in for this lane's segment
    float h = __shfl_up(Uag, 1);
    if (lane == 0) h = 0.f;
    #pragma unroll
    for (int k=0;k<PER;k++){
        Cr[base + (size_t)k*NJ] = h;
        h = fmaf(a[k], h, u[k]);
    }
}

// ============ k_scan2: thread=(c,s); apply carry, contract to y ==============
__global__ __launch_bounds__(256) void k_scan2(const float* __restrict__ dt,
    const float* __restrict__ x, const float* __restrict__ boa,
    const float* __restrict__ cmat, const float* __restrict__ logA,
    const float* __restrict__ Cr, float* __restrict__ y, int TT)
{
    const int tid = threadIdx.x;
    const int s   = tid & 15;
    const int cl  = tid >> 4;
    const int c   = blockIdx.x * 16 + cl;
    const int g   = blockIdx.y;

    const float als = -fexp2(logA[s]*LOG2E) * LOG2E;

    const int row0 = g * TT;
    const float* __restrict__ dp = dt   + (size_t)row0*CC + c;
    const float* __restrict__ xp = x    + (size_t)row0*CC + c;
    const float* __restrict__ bp = boa  + (size_t)row0*SS + s;
    const float* __restrict__ cp = cmat + (size_t)row0*SS + s;

    float h = Cr[(size_t)g*(CC*SS) + blockIdx.x*256 + tid];

    float d0 = dp[0],  x0 = xp[0],  b0 = bp[0],  c0v = cp[0];
    float d1 = dp[CC], x1 = xp[CC], b1 = bp[SS], c1v = cp[SS];

    float* __restrict__ yp = y + (size_t)row0*CC + c;

    for (int t = 0; t < TT; ++t) {
        float d2=0.f, x2=0.f, b2=0.f, c2v=0.f;
        if (t + 2 < TT) { d2 = dp[2*CC]; x2 = xp[2*CC]; b2 = bp[2*SS]; c2v = cp[2*SS]; }
        float a = fexp2(d0 * als);
        float u = fexp2(fmaf(a, b0, -b0)) * x0;
        h = fmaf(a, h, u);
        float p = c0v * h;
        p += __shfl_xor(p, 1);
        p += __shfl_xor(p, 2);
        p += __shfl_xor(p, 4);
        p += __shfl_xor(p, 8);
        if (s == 0) *yp = p;
        d0 = d1; x0 = x1; b0 = b1; c0v = c1v;
        d1 = d2; x1 = x2; b1 = b2; c1v = c2v;
        dp += CC; xp += CC; bp += SS; cp += SS;
        yp += CC;
    }
}

extern "C" void kernel_launch(void* const* d_in, const int* in_sizes, int n_in,
                              void* d_out, int out_size, void* d_ws, size_t ws_size,
                              hipStream_t stream) {
    const float* x    = (const float*)d_in[0];
    const float* logA = (const float*)d_in[1];
    const float* W_dt = (const float*)d_in[2];
    const float* b_dt = (const float*)d_in[3];
    const float* W_B  = (const float*)d_in[4];
    const float* b_B  = (const float*)d_in[5];
    const float* W_C  = (const float*)d_in[6];
    const float* b_C  = (const float*)d_in[7];
    float* y  = (float*)d_out;
    float* ws = (float*)d_ws;

    size_t need512 = ((size_t)LL*CC + 2ull*LL*SS + 3ull*512*CC*SS) * 4ull;
    const int GG = (ws_size >= need512) ? 512 : 256;
    const int TT = LL / GG;

    float* dt  = ws;
    float* boa = dt  + (size_t)LL*CC;
    float* cmv = boa + (size_t)LL*SS;
    float* Ap  = cmv + (size_t)LL*SS;
    float* Hl  = Ap  + (size_t)GG*CC*SS;
    float* Cr  = Hl  + (size_t)GG*CC*SS;

    hipLaunchKernelGGL(k_proj,  dim3(5,128), dim3(256), 0, stream,
                       x, W_dt, b_dt, W_B, b_B, W_C, b_C, logA, dt, boa, cmv);
    hipLaunchKernelGGL(k_scan1, dim3(16,GG), dim3(256), 0, stream,
                       dt, x, boa, logA, Ap, Hl, TT);
    if (GG == 512)
        hipLaunchKernelGGL(k_carry<8>, dim3(1024), dim3(256), 0, stream, Ap, Hl, Cr);
    else
        hipLaunchKernelGGL(k_carry<4>, dim3(1024), dim3(256), 0, stream, Ap, Hl, Cr);
    hipLaunchKernelGGL(k_scan2, dim3(16,GG), dim3(256), 0, stream,
                       dt, x, boa, cmv, logA, Cr, y, TT);
}

// Round 4
// 148.869 us; speedup vs baseline: 1.3469x; 1.3469x over previous
//
#include <hip/hip_runtime.h>
#include <math.h>

#define LL 8192
#define CC 256
#define SS 16
#define NJ (CC*SS)      // 4096 chains
#define GG 1024         // chunks
#define TT 8            // rows per chunk (LL/GG)
#define SEGS 16
#define PER (GG/SEGS)   // 64 chunks per carry segment

#define LOG2E 1.4426950408889634f
#define LN2   0.6931471805599453f

__device__ __forceinline__ float fexp2(float v){ return __builtin_amdgcn_exp2f(v); }
__device__ __forceinline__ float flog2v(float v){ return __builtin_amdgcn_logf(v); }

// softplus(z) = max(z,0) + ln2 * log2(1 + 2^(-|z|*log2e))
__device__ __forceinline__ float softplus(float z){
    float t = fexp2(-fabsf(z) * LOG2E);
    return fmaxf(z, 0.f) + LN2 * flog2v(1.f + t);
}

__device__ __forceinline__ void load16(float* d, const float* __restrict__ p){
    *(float4*)&d[0]  = *(const float4*)&p[0];
    *(float4*)&d[4]  = *(const float4*)&p[4];
    *(float4*)&d[8]  = *(const float4*)&p[8];
    *(float4*)&d[12] = *(const float4*)&p[12];
}

// ============ k_proj: fused GEMM producing dt (softplus), boa, cm ============
#define BM 64
#define BN 64
#define BK 32
#define XSTR 68

__global__ __launch_bounds__(256) void k_proj(
    const float* __restrict__ x,
    const float* __restrict__ Wdt, const float* __restrict__ bdt,
    const float* __restrict__ WB,  const float* __restrict__ bB,
    const float* __restrict__ WC,  const float* __restrict__ bC,
    const float* __restrict__ logA,
    float* __restrict__ dt, float* __restrict__ boa, float* __restrict__ cm)
{
    __shared__ float xs[BK*XSTR];
    __shared__ float wsd[BK*BN];

    const int tid     = threadIdx.x;
    const int colTile = blockIdx.x;
    const int row0    = blockIdx.y * BM;
    const int n0      = colTile * BN;

    const int sr  = tid >> 3;
    const int sk4 = (tid & 7) * 4;
    const int wk  = tid >> 4;
    const int wn4 = (tid & 15) * 4;
    const int tn  = tid & 15, tm = tid >> 4;

    float4 xr[2], wr[2];

    #define FETCH(k0) do {                                                     \
        _Pragma("unroll")                                                      \
        for (int h2=0; h2<2; h2++)                                             \
            xr[h2] = *(const float4*)&x[(size_t)(row0 + sr + h2*32)*CC + (k0) + sk4]; \
        _Pragma("unroll")                                                      \
        for (int h2=0; h2<2; h2++){                                            \
            int k = (k0) + wk + h2*16;                                         \
            if (colTile < 4)      wr[h2] = *(const float4*)&Wdt[(size_t)k*CC + n0 + wn4]; \
            else if (wn4 < 16)    wr[h2] = *(const float4*)&WB[(size_t)k*SS + wn4];       \
            else if (wn4 < 32)    wr[h2] = *(const float4*)&WC[(size_t)k*SS + (wn4-16)];  \
            else                  wr[h2] = make_float4(0.f,0.f,0.f,0.f);       \
        }                                                                      \
    } while(0)

    FETCH(0);

    float acc[4][4];
    #pragma unroll
    for (int r=0;r<4;r++)
        #pragma unroll
        for (int j=0;j<4;j++) acc[r][j] = 0.f;

    for (int k0 = 0; k0 < CC; k0 += BK) {
        __syncthreads();
        #pragma unroll
        for (int h2=0; h2<2; h2++){
            int r = sr + h2*32;
            xs[(sk4+0)*XSTR + r] = xr[h2].x;
            xs[(sk4+1)*XSTR + r] = xr[h2].y;
            xs[(sk4+2)*XSTR + r] = xr[h2].z;
            xs[(sk4+3)*XSTR + r] = xr[h2].w;
            *(float4*)&wsd[(wk + h2*16)*BN + wn4] = wr[h2];
        }
        __syncthreads();
        if (k0 + BK < CC) FETCH(k0 + BK);

        #pragma unroll
        for (int kk = 0; kk < BK; kk++) {
            float4 av = *(const float4*)&xs[kk*XSTR + tm*4];
            float4 bv = *(const float4*)&wsd[kk*BN  + tn*4];
            const float* ap = &av.x; const float* bp = &bv.x;
            #pragma unroll
            for (int r=0;r<4;r++)
                #pragma unroll
                for (int j=0;j<4;j++)
                    acc[r][j] = fmaf(ap[r], bp[j], acc[r][j]);
        }
    }

    const int m0 = row0 + tm*4;
    if (colTile < 4) {
        const int cg = n0 + tn*4;
        float4 bb = *(const float4*)&bdt[cg];
        const float* bbp = &bb.x;
        #pragma unroll
        for (int r=0;r<4;r++){
            float o[4];
            #pragma unroll
            for (int j=0;j<4;j++)
                o[j] = softplus(0.01f + acc[r][j] + bbp[j]);
            *(float4*)&dt[(size_t)(m0+r)*CC + cg] = make_float4(o[0],o[1],o[2],o[3]);
        }
    } else if (tn < 4) {
        const int s4 = tn*4;
        float sc[4], bv[4];
        #pragma unroll
        for (int j=0;j<4;j++){
            float A = -fexp2(logA[s4+j] * LOG2E);
            sc[j] = LOG2E / A;
            bv[j] = bB[s4+j];
        }
        #pragma unroll
        for (int r=0;r<4;r++){
            float o[4];
            #pragma unroll
            for (int j=0;j<4;j++)
                o[j] = (1.f + acc[r][j] + bv[j]) * sc[j];
            *(float4*)&boa[(size_t)(m0+r)*SS + s4] = make_float4(o[0],o[1],o[2],o[3]);
        }
    } else if (tn < 8) {
        const int s4 = tn*4 - 16;
        float bv[4];
        #pragma unroll
        for (int j=0;j<4;j++) bv[j] = bC[s4+j];
        #pragma unroll
        for (int r=0;r<4;r++){
            float o[4];
            #pragma unroll
            for (int j=0;j<4;j++)
                o[j] = acc[r][j] + bv[j];
            *(float4*)&cm[(size_t)(m0+r)*SS + s4] = make_float4(o[0],o[1],o[2],o[3]);
        }
    }
    #undef FETCH
}

// ============ k_scan1: thread=channel (16 states in regs), TT unrolled =======
__global__ __launch_bounds__(256) void k_scan1(const float* __restrict__ dt,
    const float* __restrict__ x, const float* __restrict__ boa,
    const float* __restrict__ logA,
    float* __restrict__ Ap, float* __restrict__ Hl)
{
    const int c = threadIdx.x;
    const int g = blockIdx.x;
    const int row0 = g * TT;

    float Al2[SS];
    #pragma unroll
    for (int s=0;s<SS;s++) Al2[s] = -fexp2(logA[s]*LOG2E) * LOG2E;  // A*log2e

    const float* __restrict__ dp = dt  + (size_t)row0*CC + c;
    const float* __restrict__ xp = x   + (size_t)row0*CC + c;
    const float* __restrict__ bp = boa + (size_t)row0*SS;

    float Apr[SS], h[SS];
    #pragma unroll
    for (int s=0;s<SS;s++){ Apr[s]=1.f; h[s]=0.f; }

    #pragma unroll
    for (int t=0;t<TT;t++){
        float d  = dp[t*CC];
        float xv = xp[t*CC];
        float bo[SS]; load16(bo, bp + t*SS);
        #pragma unroll
        for (int s=0;s<SS;s++){
            float a = fexp2(d * Al2[s]);
            float u = fexp2(fmaf(a, bo[s], -bo[s])) * xv;
            h[s] = fmaf(a, h[s], u);
            Apr[s] *= a;
        }
    }

    const size_t base = (size_t)g*NJ + c*SS;
    *(float4*)&Ap[base+0]  = make_float4(Apr[0],Apr[1],Apr[2],Apr[3]);
    *(float4*)&Ap[base+4]  = make_float4(Apr[4],Apr[5],Apr[6],Apr[7]);
    *(float4*)&Ap[base+8]  = make_float4(Apr[8],Apr[9],Apr[10],Apr[11]);
    *(float4*)&Ap[base+12] = make_float4(Apr[12],Apr[13],Apr[14],Apr[15]);
    *(float4*)&Hl[base+0]  = make_float4(h[0],h[1],h[2],h[3]);
    *(float4*)&Hl[base+4]  = make_float4(h[4],h[5],h[6],h[7]);
    *(float4*)&Hl[base+8]  = make_float4(h[8],h[9],h[10],h[11]);
    *(float4*)&Hl[base+12] = make_float4(h[12],h[13],h[14],h[15]);
}

// ============ k_carry: seg-parallel scan; block = 16 chains x 16 segs ========
__global__ __launch_bounds__(256) void k_carry(const float* __restrict__ Ap,
    const float* __restrict__ Hl, float* __restrict__ Cr)
{
    const int tid = threadIdx.x;
    const int jl  = tid & 15;
    const int seg = tid >> 4;
    const int j   = blockIdx.x * 16 + jl;

    const size_t base = (size_t)(seg*PER)*NJ + j;

    // phase 1: aggregate this segment (8-deep batched, coalesced in j)
    float Aag = 1.f, Uag = 0.f;
    for (int k0 = 0; k0 < PER; k0 += 8) {
        float a[8], u[8];
        #pragma unroll
        for (int i=0;i<8;i++){
            a[i] = Ap[base + (size_t)(k0+i)*NJ];
            u[i] = Hl[base + (size_t)(k0+i)*NJ];
        }
        #pragma unroll
        for (int i=0;i<8;i++){ Uag = fmaf(a[i], Uag, u[i]); Aag *= a[i]; }
    }

    // phase 2: LDS scan across segments (exclusive carry-in per segment)
    __shared__ float As[SEGS][17], Us[SEGS][17];
    As[seg][jl] = Aag; Us[seg][jl] = Uag;
    __syncthreads();
    float hin = 0.f;
    for (int t = 0; t < seg; ++t)
        hin = fmaf(As[t][jl], hin, Us[t][jl]);

    // phase 3: re-read (L2-hot) and emit per-chunk carry-in
    float h = hin;
    for (int k0 = 0; k0 < PER; k0 += 8) {
        float a[8], u[8];
        #pragma unroll
        for (int i=0;i<8;i++){
            a[i] = Ap[base + (size_t)(k0+i)*NJ];
            u[i] = Hl[base + (size_t)(k0+i)*NJ];
        }
        #pragma unroll
        for (int i=0;i<8;i++){
            Cr[base + (size_t)(k0+i)*NJ] = h;
            h = fmaf(a[i], h, u[i]);
        }
    }
}

// ============ k_scan2: thread=channel; apply carry, contract to y ============
__global__ __launch_bounds__(256) void k_scan2(const float* __restrict__ dt,
    const float* __restrict__ x, const float* __restrict__ boa,
    const float* __restrict__ cmat, const float* __restrict__ logA,
    const float* __restrict__ Cr, float* __restrict__ y)
{
    const int c = threadIdx.x;
    const int g = blockIdx.x;
    const int row0 = g * TT;

    float Al2[SS];
    #pragma unroll
    for (int s=0;s<SS;s++) Al2[s] = -fexp2(logA[s]*LOG2E) * LOG2E;

    const float* __restrict__ dp = dt   + (size_t)row0*CC + c;
    const float* __restrict__ xp = x    + (size_t)row0*CC + c;
    const float* __restrict__ bp = boa  + (size_t)row0*SS;
    const float* __restrict__ cp = cmat + (size_t)row0*SS;
    float* __restrict__ yp = y + (size_t)row0*CC + c;

    float h[SS];
    load16(h, &Cr[(size_t)g*NJ + c*SS]);

    #pragma unroll
    for (int t=0;t<TT;t++){
        float d  = dp[t*CC];
        float xv = xp[t*CC];
        float bo[SS]; load16(bo, bp + t*SS);
        float cm[SS]; load16(cm, cp + t*SS);
        float yv = 0.f;
        #pragma unroll
        for (int s=0;s<SS;s++){
            float a = fexp2(d * Al2[s]);
            float u = fexp2(fmaf(a, bo[s], -bo[s])) * xv;
            h[s] = fmaf(a, h[s], u);
            yv = fmaf(cm[s], h[s], yv);
        }
        yp[t*CC] = yv;
    }
}

extern "C" void kernel_launch(void* const* d_in, const int* in_sizes, int n_in,
                              void* d_out, int out_size, void* d_ws, size_t ws_size,
                              hipStream_t stream) {
    const float* x    = (const float*)d_in[0];
    const float* logA = (const float*)d_in[1];
    const float* W_dt = (const float*)d_in[2];
    const float* b_dt = (const float*)d_in[3];
    const float* W_B  = (const float*)d_in[4];
    const float* b_B  = (const float*)d_in[5];
    const float* W_C  = (const float*)d_in[6];
    const float* b_C  = (const float*)d_in[7];
    float* y  = (float*)d_out;
    float* ws = (float*)d_ws;

    float* dt  = ws;                         // L*C      8 MB
    float* boa = dt  + (size_t)LL*CC;        // L*S
    float* cmv = boa + (size_t)LL*SS;        // L*S
    float* Ap  = cmv + (size_t)LL*SS;        // GG*NJ    16 MB
    float* Hl  = Ap  + (size_t)GG*NJ;        // GG*NJ    16 MB
    float* Cr  = Hl  + (size_t)GG*NJ;        // GG*NJ    16 MB   (~57 MB total)

    hipLaunchKernelGGL(k_proj,  dim3(5,128), dim3(256), 0, stream,
                       x, W_dt, b_dt, W_B, b_B, W_C, b_C, logA, dt, boa, cmv);
    hipLaunchKernelGGL(k_scan1, dim3(GG),    dim3(256), 0, stream,
                       dt, x, boa, logA, Ap, Hl);
    hipLaunchKernelGGL(k_carry, dim3(NJ/16), dim3(256), 0, stream, Ap, Hl, Cr);
    hipLaunchKernelGGL(k_scan2, dim3(GG),    dim3(256), 0, stream,
                       dt, x, boa, cmv, logA, Cr, y);
}

// Round 6
// 138.562 us; speedup vs baseline: 1.4471x; 1.0744x over previous
//
#include <hip/hip_runtime.h>
#include <hip/hip_bf16.h>
#include <math.h>

#define LL 8192
#define CC 256
#define SS 16
#define NJ (CC*SS)      // 4096 chains
#define GG 1024         // chunks
#define TT 8            // rows per chunk
#define SEGS 16
#define PER (GG/SEGS)   // 64 chunks per carry segment

#define LOG2E 1.4426950408889634f
#define LN2   0.6931471805599453f

typedef __attribute__((ext_vector_type(8))) short short8;
typedef __attribute__((ext_vector_type(4))) float floatx4;

__device__ __forceinline__ float fexp2(float v){ return __builtin_amdgcn_exp2f(v); }
__device__ __forceinline__ float flog2v(float v){ return __builtin_amdgcn_logf(v); }

__device__ __forceinline__ float softplus(float z){
    float t = fexp2(-fabsf(z) * LOG2E);
    return fmaxf(z, 0.f) + LN2 * flog2v(1.f + t);
}

__device__ __forceinline__ void load16(float* d, const float* __restrict__ p){
    *(float4*)&d[0]  = *(const float4*)&p[0];
    *(float4*)&d[4]  = *(const float4*)&p[4];
    *(float4*)&d[8]  = *(const float4*)&p[8];
    *(float4*)&d[12] = *(const float4*)&p[12];
}

__device__ __forceinline__ unsigned short f2b(float f){
    __hip_bfloat16 h = __float2bfloat16(f);
    return *(unsigned short*)&h;
}
__device__ __forceinline__ float b2f(unsigned short u){
    __hip_bfloat16 h = *(__hip_bfloat16*)&u;
    return __bfloat162float(h);
}

// ============ k_cast: build wbT_hi/lo[n][k] bf16, n in [0,288) ===============
// n<256: W_dt[k][n]; [256,272): W_B[k][n-256]; [272,288): W_C[k][n-272]
__global__ __launch_bounds__(256) void k_cast(
    const float* __restrict__ Wdt, const float* __restrict__ WB,
    const float* __restrict__ WC,
    unsigned short* __restrict__ wbh, unsigned short* __restrict__ wbl)
{
    const int idx = blockIdx.x*256 + threadIdx.x;   // 0..73727
    const int k = idx & 255;
    const int n = idx >> 8;
    float v;
    if (n < 256)      v = Wdt[(size_t)k*CC + n];
    else if (n < 272) v = WB[(size_t)k*SS + (n-256)];
    else              v = WC[(size_t)k*SS + (n-272)];
    unsigned short hi = f2b(v);
    wbh[(size_t)n*256 + k] = hi;
    wbl[(size_t)n*256 + k] = f2b(v - b2f(hi));
}

// ============ k_mm: split-bf16 MFMA GEMM, out = x @ [Wdt|WB|WC] ==============
// z = xh@Wh + xh@Wl + xl@Wh  (error ~2^-16, fp32-like)
// grid (9, 128): bx = N-tile (BN=32), by = M-tile (BM=64). 4 waves/block.
#define MBM 64
#define MBN 32
#define MBK 64
#define ASTR 72   // bf16 elems; 144 B row stride (16B-aligned, 2-way banks max)

__global__ __launch_bounds__(256,4) void k_mm(
    const float* __restrict__ x,
    const unsigned short* __restrict__ wbh, const unsigned short* __restrict__ wbl,
    const float* __restrict__ bdt, const float* __restrict__ bB,
    const float* __restrict__ bC, const float* __restrict__ logA,
    float* __restrict__ dt, float* __restrict__ boa, float* __restrict__ cm)
{
    __shared__ unsigned short Ah[MBM*ASTR];   // [m][k] hi
    __shared__ unsigned short Al[MBM*ASTR];   // [m][k] lo
    __shared__ unsigned short Bh[MBN*ASTR];   // [n][k] hi
    __shared__ unsigned short Bl[MBN*ASTR];   // [n][k] lo

    const int tid  = threadIdx.x;
    const int n0   = blockIdx.x * MBN;
    const int row0 = blockIdx.y * MBM;

    const int lane = tid & 63;
    const int wv   = tid >> 6;
    const int wm   = wv >> 1;          // 0..1  (M half)
    const int wn   = wv & 1;           // 0..1  (N half)
    const int m16  = lane & 15;
    const int q    = lane >> 4;

    floatx4 acc[2];
    acc[0] = (floatx4){0.f,0.f,0.f,0.f};
    acc[1] = (floatx4){0.f,0.f,0.f,0.f};

    for (int k0 = 0; k0 < CC; k0 += MBK) {
        __syncthreads();
        // stage A: 64 rows x 64 k, fp32 -> (hi,lo) bf16. 512 chunks of 8 elems.
        #pragma unroll
        for (int h2 = 0; h2 < 2; h2++){
            int chunk = tid + h2*256;
            int r    = chunk >> 3;
            int koff = (chunk & 7) * 8;
            float4 f0 = *(const float4*)&x[(size_t)(row0+r)*CC + k0 + koff];
            float4 f1 = *(const float4*)&x[(size_t)(row0+r)*CC + k0 + koff + 4];
            const float* f = &f0.x;   // f0,f1 contiguous on stack? safer: copy
            float fv[8] = {f0.x,f0.y,f0.z,f0.w,f1.x,f1.y,f1.z,f1.w};
            (void)f;
            unsigned short hs[8], ls[8];
            #pragma unroll
            for (int i=0;i<8;i++){
                hs[i] = f2b(fv[i]);
                ls[i] = f2b(fv[i] - b2f(hs[i]));
            }
            uint4 ph, pl;
            ph.x = (unsigned)hs[0] | ((unsigned)hs[1] << 16);
            ph.y = (unsigned)hs[2] | ((unsigned)hs[3] << 16);
            ph.z = (unsigned)hs[4] | ((unsigned)hs[5] << 16);
            ph.w = (unsigned)hs[6] | ((unsigned)hs[7] << 16);
            pl.x = (unsigned)ls[0] | ((unsigned)ls[1] << 16);
            pl.y = (unsigned)ls[2] | ((unsigned)ls[3] << 16);
            pl.z = (unsigned)ls[4] | ((unsigned)ls[5] << 16);
            pl.w = (unsigned)ls[6] | ((unsigned)ls[7] << 16);
            *(uint4*)&Ah[r*ASTR + koff] = ph;
            *(uint4*)&Al[r*ASTR + koff] = pl;
        }
        // stage B: 32 n x 64 k from wbT (bf16 [n][k]): 256 chunks of 8 elems
        {
            int n    = tid >> 3;
            int koff = (tid & 7) * 8;
            *(uint4*)&Bh[n*ASTR + koff] = *(const uint4*)&wbh[(size_t)(n0+n)*256 + k0 + koff];
            *(uint4*)&Bl[n*ASTR + koff] = *(const uint4*)&wbl[(size_t)(n0+n)*256 + k0 + koff];
        }
        __syncthreads();

        #pragma unroll
        for (int ks = 0; ks < MBK; ks += 32) {
            short8 bh = *(const short8*)&Bh[(wn*16 + m16)*ASTR + ks + q*8];
            short8 bl = *(const short8*)&Bl[(wn*16 + m16)*ASTR + ks + q*8];
            #pragma unroll
            for (int mt = 0; mt < 2; mt++){
                short8 ah = *(const short8*)&Ah[(wm*32 + mt*16 + m16)*ASTR + ks + q*8];
                short8 al = *(const short8*)&Al[(wm*32 + mt*16 + m16)*ASTR + ks + q*8];
                acc[mt] = __builtin_amdgcn_mfma_f32_16x16x32_bf16(al, bh, acc[mt], 0, 0, 0);
                acc[mt] = __builtin_amdgcn_mfma_f32_16x16x32_bf16(ah, bl, acc[mt], 0, 0, 0);
                acc[mt] = __builtin_amdgcn_mfma_f32_16x16x32_bf16(ah, bh, acc[mt], 0, 0, 0);
            }
        }
    }

    // epilogue: C/D layout col=lane&15, row=q*4+reg  [m89/m91 verified]
    const int col = n0 + wn*16 + m16;
    if (col < 256) {
        float bias = bdt[col];
        #pragma unroll
        for (int mt = 0; mt < 2; mt++){
            #pragma unroll
            for (int r = 0; r < 4; r++){
                int row = row0 + wm*32 + mt*16 + q*4 + r;
                dt[(size_t)row*CC + col] = softplus(0.01f + acc[mt][r] + bias);
            }
        }
    } else if (col < 272) {      // boa
        int s = col - 256;
        float A = -fexp2(logA[s] * LOG2E);
        float sc = LOG2E / A;
        float bias = bB[s];
        #pragma unroll
        for (int mt = 0; mt < 2; mt++){
            #pragma unroll
            for (int r = 0; r < 4; r++){
                int row = row0 + wm*32 + mt*16 + q*4 + r;
                boa[(size_t)row*SS + s] = (1.f + acc[mt][r] + bias) * sc;
            }
        }
    } else {                      // cm
        int s = col - 272;
        float bias = bC[s];
        #pragma unroll
        for (int mt = 0; mt < 2; mt++){
            #pragma unroll
            for (int r = 0; r < 4; r++){
                int row = row0 + wm*32 + mt*16 + q*4 + r;
                cm[(size_t)row*SS + s] = acc[mt][r] + bias;
            }
        }
    }
}

// ============ k_scan1: thread=channel; boa staged in LDS =====================
__global__ __launch_bounds__(256) void k_scan1(const float* __restrict__ dt,
    const float* __restrict__ x, const float* __restrict__ boa,
    const float* __restrict__ logA,
    float* __restrict__ Ap, float* __restrict__ Hl)
{
    const int c = threadIdx.x;
    const int g = blockIdx.x;
    const int row0 = g * TT;

    __shared__ float boS[TT*SS];
    if (c < TT*SS) boS[c] = boa[(size_t)row0*SS + c];

    float Al2[SS];
    #pragma unroll
    for (int s=0;s<SS;s++) Al2[s] = -fexp2(logA[s]*LOG2E) * LOG2E;  // A*log2e

    const float* __restrict__ dp = dt + (size_t)row0*CC + c;
    const float* __restrict__ xp = x  + (size_t)row0*CC + c;

    float Apr[SS], h[SS];
    #pragma unroll
    for (int s=0;s<SS;s++){ Apr[s]=1.f; h[s]=0.f; }

    __syncthreads();

    #pragma unroll
    for (int t=0;t<TT;t++){
        float d  = dp[t*CC];
        float xv = xp[t*CC];
        float bo[SS]; load16(bo, &boS[t*SS]);
        #pragma unroll
        for (int s=0;s<SS;s++){
            float a = fexp2(d * Al2[s]);
            float u = fexp2(fmaf(a, bo[s], -bo[s])) * xv;
            h[s] = fmaf(a, h[s], u);
            Apr[s] *= a;
        }
    }

    const size_t base = (size_t)g*NJ + c*SS;
    *(float4*)&Ap[base+0]  = make_float4(Apr[0],Apr[1],Apr[2],Apr[3]);
    *(float4*)&Ap[base+4]  = make_float4(Apr[4],Apr[5],Apr[6],Apr[7]);
    *(float4*)&Ap[base+8]  = make_float4(Apr[8],Apr[9],Apr[10],Apr[11]);
    *(float4*)&Ap[base+12] = make_float4(Apr[12],Apr[13],Apr[14],Apr[15]);
    *(float4*)&Hl[base+0]  = make_float4(h[0],h[1],h[2],h[3]);
    *(float4*)&Hl[base+4]  = make_float4(h[4],h[5],h[6],h[7]);
    *(float4*)&Hl[base+8]  = make_float4(h[8],h[9],h[10],h[11]);
    *(float4*)&Hl[base+12] = make_float4(h[12],h[13],h[14],h[15]);
}

// ============ k_carry: seg-parallel scan; block = 16 chains x 16 segs ========
__global__ __launch_bounds__(256) void k_carry(const float* __restrict__ Ap,
    const float* __restrict__ Hl, float* __restrict__ Cr)
{
    const int tid = threadIdx.x;
    const int jl  = tid & 15;
    const int seg = tid >> 4;
    const int j   = blockIdx.x * 16 + jl;

    const size_t base = (size_t)(seg*PER)*NJ + j;

    float Aag = 1.f, Uag = 0.f;
    for (int k0 = 0; k0 < PER; k0 += 8) {
        float a[8], u[8];
        #pragma unroll
        for (int i=0;i<8;i++){
            a[i] = Ap[base + (size_t)(k0+i)*NJ];
            u[i] = Hl[base + (size_t)(k0+i)*NJ];
        }
        #pragma unroll
        for (int i=0;i<8;i++){ Uag = fmaf(a[i], Uag, u[i]); Aag *= a[i]; }
    }

    __shared__ float As[SEGS][17], Us[SEGS][17];
    As[seg][jl] = Aag; Us[seg][jl] = Uag;
    __syncthreads();
    float hin = 0.f;
    for (int t = 0; t < seg; ++t)
        hin = fmaf(As[t][jl], hin, Us[t][jl]);

    float h = hin;
    for (int k0 = 0; k0 < PER; k0 += 8) {
        float a[8], u[8];
        #pragma unroll
        for (int i=0;i<8;i++){
            a[i] = Ap[base + (size_t)(k0+i)*NJ];
            u[i] = Hl[base + (size_t)(k0+i)*NJ];
        }
        #pragma unroll
        for (int i=0;i<8;i++){
            Cr[base + (size_t)(k0+i)*NJ] = h;
            h = fmaf(a[i], h, u[i]);
        }
    }
}

// ============ k_scan2: thread=channel; boa/cm staged in LDS ==================
__global__ __launch_bounds__(256) void k_scan2(const float* __restrict__ dt,
    const float* __restrict__ x, const float* __restrict__ boa,
    const float* __restrict__ cmat, const float* __restrict__ logA,
    const float* __restrict__ Cr, float* __restrict__ y)
{
    const int c = threadIdx.x;
    const int g = blockIdx.x;
    const int row0 = g * TT;

    __shared__ float boS[TT*SS], cmS[TT*SS];
    if (c < TT*SS)       boS[c]        = boa [(size_t)row0*SS + c];
    else                 cmS[c-TT*SS]  = cmat[(size_t)row0*SS + (c-TT*SS)];

    float Al2[SS];
    #pragma unroll
    for (int s=0;s<SS;s++) Al2[s] = -fexp2(logA[s]*LOG2E) * LOG2E;

    const float* __restrict__ dp = dt + (size_t)row0*CC + c;
    const float* __restrict__ xp = x  + (size_t)row0*CC + c;
    float* __restrict__ yp = y + (size_t)row0*CC + c;

    float h[SS];
    load16(h, &Cr[(size_t)g*NJ + c*SS]);

    __syncthreads();

    #pragma unroll
    for (int t=0;t<TT;t++){
        float d  = dp[t*CC];
        float xv = xp[t*CC];
        float bo[SS]; load16(bo, &boS[t*SS]);
        float cmv[SS]; load16(cmv, &cmS[t*SS]);
        float yv = 0.f;
        #pragma unroll
        for (int s=0;s<SS;s++){
            float a = fexp2(d * Al2[s]);
            float u = fexp2(fmaf(a, bo[s], -bo[s])) * xv;
            h[s] = fmaf(a, h[s], u);
            yv = fmaf(cmv[s], h[s], yv);
        }
        yp[t*CC] = yv;
    }
}

extern "C" void kernel_launch(void* const* d_in, const int* in_sizes, int n_in,
                              void* d_out, int out_size, void* d_ws, size_t ws_size,
                              hipStream_t stream) {
    const float* x    = (const float*)d_in[0];
    const float* logA = (const float*)d_in[1];
    const float* W_dt = (const float*)d_in[2];
    const float* b_dt = (const float*)d_in[3];
    const float* W_B  = (const float*)d_in[4];
    const float* b_B  = (const float*)d_in[5];
    const float* W_C  = (const float*)d_in[6];
    const float* b_C  = (const float*)d_in[7];
    float* y  = (float*)d_out;
    float* ws = (float*)d_ws;

    float* dt  = ws;                          // L*C
    float* boa = dt  + (size_t)LL*CC;         // L*S
    float* cmv = boa + (size_t)LL*SS;         // L*S
    float* Ap  = cmv + (size_t)LL*SS;         // GG*NJ
    float* Hl  = Ap  + (size_t)GG*NJ;         // GG*NJ
    float* Cr  = Hl  + (size_t)GG*NJ;         // GG*NJ
    unsigned short* wbh = (unsigned short*)(Cr + (size_t)GG*NJ);   // 288*256
    unsigned short* wbl = wbh + 288*256;

    hipLaunchKernelGGL(k_cast, dim3(288), dim3(256), 0, stream, W_dt, W_B, W_C, wbh, wbl);
    hipLaunchKernelGGL(k_mm,   dim3(9,128), dim3(256), 0, stream,
                       x, wbh, wbl, b_dt, b_B, b_C, logA, dt, boa, cmv);
    hipLaunchKernelGGL(k_scan1, dim3(GG),    dim3(256), 0, stream,
                       dt, x, boa, logA, Ap, Hl);
    hipLaunchKernelGGL(k_carry, dim3(NJ/16), dim3(256), 0, stream, Ap, Hl, Cr);
    hipLaunchKernelGGL(k_scan2, dim3(GG),    dim3(256), 0, stream,
                       dt, x, boa, cmv, logA, Cr, y);
}